// Round 6
// baseline (999.417 us; speedup 1.0000x reference)
//
#include <hip/hip_runtime.h>

#define NV 20000
#define NNZE 6400000
#define KD 1280          // K = B * C_IN * R_IN
#define ND 512           // C_OUT * R_OUT
#define MROWS 20000
#define NR 1600000       // NV * 80 agg rows
#define HALF 800000      // rows per sort pass
#define NBLK 391         // ceil(HALF / 2048)

typedef __attribute__((ext_vector_type(8))) short short8;
typedef __attribute__((ext_vector_type(4))) float f32x4;

// exact RNE f32 -> bf16 (finite inputs)
static __device__ __forceinline__ unsigned short f2bf(float f) {
    unsigned int u = __float_as_uint(f);
    return (unsigned short)((u + 0x7FFFu + ((u >> 16) & 1u)) >> 16);
}

__global__ __launch_bounds__(256) void zero_u32(unsigned int* __restrict__ p, int n) {
    int i = blockIdx.x * 256 + threadIdx.x;
    if (i < n) p[i] = 0u;
}

// lwT[n][k] (bf16, n-major) where lw[k][n] = weights[o*KD + src], n = o*16+j
__global__ __launch_bounds__(256) void build_lwT_kernel(
        const float* __restrict__ w, unsigned short* __restrict__ lwT) {
    int idx = blockIdx.x * 256 + threadIdx.x;           // < 512*1280
    int n = idx / KD;
    int k = idx - n * KD;
    int o = n >> 4, j = n & 15;
    int ci = k / 80;
    int i  = k - ci * 80;
    int t  = i / 5, p = i - t * 5;
    int src = ci * 80 + ((t + j) & 15) * 5 + p;
    lwT[idx] = f2bf(w[o * KD + src]);
}

// count edges per row (rows in [lo,hi)); A is the pass-local counter array
__global__ __launch_bounds__(256) void hist_kernel(
        const int* __restrict__ rows, unsigned int* __restrict__ A, int lo, int hi) {
    int e = blockIdx.x * 256 + threadIdx.x;             // grid exact = NNZE
    int r = rows[e];
    if (r >= lo && r < hi) atomicAdd(&A[r - lo], 1u);
}

// in-place block-local exclusive scan of A[HALF]; bsum[b] = block total
__global__ __launch_bounds__(256) void scan1_kernel(
        unsigned int* __restrict__ A, unsigned int* __restrict__ bsum) {
    __shared__ unsigned int sh[256];
    int tid  = threadIdx.x;
    int base = blockIdx.x * 2048 + tid * 8;
    unsigned int v[8];
    unsigned int run = 0;
#pragma unroll
    for (int q = 0; q < 8; q++) {
        unsigned int t = (base + q < HALF) ? A[base + q] : 0u;
        v[q] = run;                 // thread-local exclusive
        run += t;
    }
    sh[tid] = run;
    __syncthreads();
    unsigned int own = run;
    for (int ofs = 1; ofs < 256; ofs <<= 1) {           // Hillis-Steele inclusive
        unsigned int t = (tid >= ofs) ? sh[tid - ofs] : 0u;
        __syncthreads();
        sh[tid] += t;
        __syncthreads();
    }
    unsigned int excl = sh[tid] - own;
#pragma unroll
    for (int q = 0; q < 8; q++)
        if (base + q < HALF) A[base + q] = excl + v[q];
    if (tid == 255) bsum[blockIdx.x] = sh[255];
}

// exclusive scan of bsum[NBLK] in place (single block)
__global__ __launch_bounds__(512) void scan2_kernel(unsigned int* __restrict__ bsum) {
    __shared__ unsigned int sh[512];
    int tid = threadIdx.x;
    unsigned int v = (tid < NBLK) ? bsum[tid] : 0u;
    sh[tid] = v;
    __syncthreads();
    for (int ofs = 1; ofs < 512; ofs <<= 1) {
        unsigned int t = (tid >= ofs) ? sh[tid - ofs] : 0u;
        __syncthreads();
        sh[tid] += t;
        __syncthreads();
    }
    if (tid < NBLK) bsum[tid] = sh[tid] - v;            // exclusive
}

// scatter edges into row-sorted order. pos = global excl prefix + fetch-add.
// After this kernel: A[i] = local_excl[i] + count[i]  (used by gather below).
__global__ __launch_bounds__(256) void reorder_kernel(
        const int* __restrict__ rows, const float* __restrict__ vals,
        const int* __restrict__ cols, unsigned int* __restrict__ A,
        const unsigned int* __restrict__ bsum, uint2* __restrict__ sorted,
        int lo, int hi) {
    int e = blockIdx.x * 256 + threadIdx.x;             // grid exact = NNZE
    int r = rows[e];
    if (r >= lo && r < hi) {
        int i = r - lo;
        unsigned int pos = bsum[i >> 11] + atomicAdd(&A[i], 1u);
        sorted[pos] = make_uint2(__float_as_uint(vals[e]), (unsigned int)cols[e]);
    }
}

// 16 threads per row (one per channel): agg[row][ch] = sum_seg val * x[col][ch]
// start(i) = F_excl(i) = A[i-1]+bsum[(i-1)>>11] (A now holds local incl prefix)
__global__ __launch_bounds__(256) void gather_kernel(
        const uint2* __restrict__ sorted, const unsigned int* __restrict__ A,
        const unsigned int* __restrict__ bsum, const float* __restrict__ x,
        unsigned short* __restrict__ agg, int lo) {
    int gt = blockIdx.x * 256 + threadIdx.x;            // grid exact = HALF*16
    int i  = gt >> 4;
    int ch = gt & 15;
    unsigned int start = (i > 0) ? (A[i - 1] + bsum[(i - 1) >> 11]) : 0u;
    unsigned int end   = A[i] + bsum[i >> 11];
    float acc = 0.f;
    for (unsigned int p = start; p < end; p++) {
        uint2 s = sorted[p];
        acc = fmaf(__uint_as_float(s.x), x[(s.y << 4) + ch], acc);
    }
    agg[((size_t)(lo + i) << 4) + ch] = f2bf(acc);
}

// C[M][512] = Abf[M][1280] * lwT^T ; bf16 MFMA 16x16x32, 128x128 tile, BK=64.
// Both operands staged via global_load_lds (linear LDS dest, inverse-pre-swizzled
// global source, swizzle cb ^= (row&7)<<4). A rows >= MROWS clamp to MROWS-1
// (epilogue masks those stores).
__global__ __launch_bounds__(256) void gemm_kernel(
        const unsigned short* __restrict__ Abf, const unsigned short* __restrict__ lwT,
        float* __restrict__ C) {
    __shared__ __align__(16) char lds[2 * 128 * 64 * 2];   // As 16KB | Bs 16KB
    char* As = lds;
    char* Bs = lds + 16384;

    int tid  = threadIdx.x;
    int lane = tid & 63;
    int wid  = tid >> 6;
    int wr = wid >> 1, wc = wid & 1;       // 2x2 waves, 64x64 each
    int m0 = blockIdx.x * 128;
    int n0 = blockIdx.y * 128;
    int l15 = lane & 15;
    int l4  = lane >> 4;

    f32x4 acc[4][4] = {};

    for (int k0 = 0; k0 < KD; k0 += 64) {
#pragma unroll
        for (int rd = 0; rd < 4; rd++) {
            int idx  = rd * 256 + tid;
            int trow = idx >> 3;                  // 0..127 (LDS row)
            int cb   = (idx & 7) * 16;            // byte in 128B row slice
            int swz  = cb ^ ((trow & 7) << 4);
            int gr   = m0 + trow;
            if (gr > MROWS - 1) gr = MROWS - 1;   // clamp; stores masked later
            size_t asrc = (size_t)gr * (KD * 2) + (size_t)(k0 * 2) + swz;
            __builtin_amdgcn_global_load_lds(
                (const __attribute__((address_space(1))) void*)((const char*)Abf + asrc),
                (__attribute__((address_space(3))) void*)(As + rd * 4096 + wid * 1024),
                16, 0, 0);
            size_t bsrc = (size_t)(n0 + trow) * (KD * 2) + (size_t)(k0 * 2) + swz;
            __builtin_amdgcn_global_load_lds(
                (const __attribute__((address_space(1))) void*)((const char*)lwT + bsrc),
                (__attribute__((address_space(3))) void*)(Bs + rd * 4096 + wid * 1024),
                16, 0, 0);
        }

        __syncthreads();   // compiler drains vmcnt before barrier (proven R4)

#pragma unroll
        for (int ks = 0; ks < 2; ks++) {
            short8 af[4], bf[4];
            int kb = ks * 64 + l4 * 16;
#pragma unroll
            for (int m = 0; m < 4; m++) {
                int r = wr * 64 + m * 16 + l15;
                af[m] = *(const short8*)(As + r * 128 + (kb ^ ((r & 7) << 4)));
            }
#pragma unroll
            for (int n = 0; n < 4; n++) {
                int r = wc * 64 + n * 16 + l15;
                bf[n] = *(const short8*)(Bs + r * 128 + (kb ^ ((r & 7) << 4)));
            }
#pragma unroll
            for (int m = 0; m < 4; m++)
#pragma unroll
                for (int n = 0; n < 4; n++)
                    acc[m][n] = __builtin_amdgcn_mfma_f32_16x16x32_bf16(
                                    af[m], bf[n], acc[m][n], 0, 0, 0);
        }

        __syncthreads();
    }

    // epilogue: D col = lane&15, row = (lane>>4)*4 + reg
#pragma unroll
    for (int m = 0; m < 4; m++) {
        int row_b = m0 + wr * 64 + m * 16 + l4 * 4;
#pragma unroll
        for (int n = 0; n < 4; n++) {
            int col = n0 + wc * 64 + n * 16 + l15;
#pragma unroll
            for (int r = 0; r < 4; r++) {
                int row = row_b + r;
                if (row < MROWS) C[(size_t)row * ND + col] = acc[m][n][r];
            }
        }
    }
}

extern "C" void kernel_launch(void* const* d_in, const int* in_sizes, int n_in,
                              void* d_out, int out_size, void* d_ws, size_t ws_size,
                              hipStream_t stream) {
    const float* x         = (const float*)d_in[0];
    const float* weights   = (const float*)d_in[1];
    const float* conn_vals = (const float*)d_in[2];
    const int*   conn_rows = (const int*)d_in[3];
    const int*   conn_cols = (const int*)d_in[4];
    float* out = (float*)d_out;

    // ws layout (82.1 MB total, all 16B-aligned):
    char* ws = (char*)d_ws;
    unsigned short* agg    = (unsigned short*)ws;              // 51,200,000 B (NR*16 bf16)
    uint2*          sorted = (uint2*)(ws + 51200000);          // 26,400,000 B
    unsigned int*   A      = (unsigned int*)(ws + 77600000);   //  3,200,000 B
    unsigned int*   bsum   = (unsigned int*)(ws + 80800000);   //      2,048 B
    unsigned short* lwT    = (unsigned short*)(ws + 80802048); //  1,310,720 B

    hipLaunchKernelGGL(build_lwT_kernel, dim3((ND * KD) / 256), dim3(256), 0, stream,
                       weights, lwT);

    for (int pass = 0; pass < 2; pass++) {
        int lo = pass * HALF, hi = lo + HALF;
        hipLaunchKernelGGL(zero_u32, dim3(HALF / 256 + 1), dim3(256), 0, stream, A, HALF);
        hipLaunchKernelGGL(hist_kernel, dim3(NNZE / 256), dim3(256), 0, stream,
                           conn_rows, A, lo, hi);
        hipLaunchKernelGGL(scan1_kernel, dim3(NBLK), dim3(256), 0, stream, A, bsum);
        hipLaunchKernelGGL(scan2_kernel, dim3(1), dim3(512), 0, stream, bsum);
        hipLaunchKernelGGL(reorder_kernel, dim3(NNZE / 256), dim3(256), 0, stream,
                           conn_rows, conn_vals, conn_cols, A, bsum, sorted, lo, hi);
        hipLaunchKernelGGL(gather_kernel, dim3((HALF * 16) / 256), dim3(256), 0, stream,
                           sorted, A, bsum, x, agg, lo);
    }

    hipLaunchKernelGGL(gemm_kernel, dim3((MROWS + 127) / 128, ND / 128), dim3(256),
                       0, stream, agg, lwT, out);
}